// Round 8
// baseline (236.061 us; speedup 1.0000x reference)
//
#include <hip/hip_runtime.h>

#define IN_DIM  2048
#define OUT_DIM 4096

typedef float     f32x4 __attribute__((ext_vector_type(4)));
typedef long long llx2  __attribute__((ext_vector_type(2)));

// pack 4 fp32 -> 4 fp8 e4m3 (RNE, HW)
__device__ __forceinline__ unsigned int pk4(float a, float b, float c, float d) {
    int v = __builtin_amdgcn_cvt_pk_fp8_f32(a, b, 0, false);   // bytes 0-1
    v     = __builtin_amdgcn_cvt_pk_fp8_f32(c, d, v, true);    // bytes 2-3
    return (unsigned int)v;
}

// async global->LDS, 16B/lane; LDS dest must be wave-uniform base + lane*16
__device__ __forceinline__ void async16(const void* g, void* l) {
    __builtin_amdgcn_global_load_lds(
        (const __attribute__((address_space(1))) unsigned int*)g,
        (__attribute__((address_space(3))) unsigned int*)l,
        16, 0, 0);
}

// 256B-superblock granule layout for fp8 rows (K-split-4 GEMM):
// super = 256 k-elems = 8 k-blocks of 32. 16B granule at position p = w*4+qd
// (w=wave 0..3, qd=quad) holds [block 2w, quad qd, 8B][block 2w+1, quad qd, 8B]
// -> one ds_read_b128 = both K=32 fp8 fragments of wave w's k-block pair.
// goff8(c): byte offset of the 8-elem chunk c (c = k>>3) within its row.
__device__ __forceinline__ int goff8(int c) {
    const int cl  = c & 31;
    const int blk = cl >> 2, qd = cl & 3;
    return (c >> 5) * 256 + ((blk >> 1) * 4 + qd) * 16 + (blk & 1) * 8;
}

// --------------------------------------------------------------------------
// Kernel 1: fused prep.
//  z<2  : transpose — W [4096][2048] fp32 -> protos fp8 (x16 scale, goff8
//         layout), protos[2c+r][d] = fp8(16*W[r*2048+d][c]); exact fp32
//         partial sumsq -> psq_part[dtile][o] (no atomics, no zeroing).
//  z==2 : xcast — x row b -> xb fp8 (goff8 layout), x_sq[b] exact fp32.
// grid (32, 32, 3) x 256 threads
// --------------------------------------------------------------------------
extern "C" __global__ __launch_bounds__(256) void prep(
        const float* __restrict__ W, const float* __restrict__ x,
        unsigned char* __restrict__ protos, unsigned char* __restrict__ xb,
        float* __restrict__ psq_part, float* __restrict__ x_sq) {
    __shared__ float tile[64][65];   // [d][c], +1 pad (z==2 uses [0][0..3])
    const int t = threadIdx.x;

    if (blockIdx.z == 2) {
        const int b = blockIdx.x + 32 * blockIdx.y;
        const float* xp = x + (size_t)b * IN_DIM + t * 8;
        const float4 v0 = ((const float4*)xp)[0];
        const float4 v1 = ((const float4*)xp)[1];
        uint2 pk;
        pk.x = pk4(v0.x, v0.y, v0.z, v0.w);
        pk.y = pk4(v1.x, v1.y, v1.z, v1.w);
        *(uint2*)(xb + (size_t)b * IN_DIM + goff8(t)) = pk;   // 8B store

        float s = v0.x * v0.x + v0.y * v0.y + v0.z * v0.z + v0.w * v0.w
                + v1.x * v1.x + v1.y * v1.y + v1.z * v1.z + v1.w * v1.w;
#pragma unroll
        for (int off = 32; off > 0; off >>= 1) s += __shfl_down(s, off);
        const int lane = t & 63, w = t >> 6;
        if (lane == 0) tile[0][w] = s;
        __syncthreads();
        if (t == 0) x_sq[b] = tile[0][0] + tile[0][1] + tile[0][2] + tile[0][3];
        return;
    }

    const int r  = blockIdx.z;
    const int c0 = blockIdx.x * 64;
    const int d0 = blockIdx.y * 64;
    const int g  = t >> 4;
    const int cc = (t & 15) * 4;

    const float* Wp = W + (size_t)(r * IN_DIM + d0 + g) * IN_DIM + c0 + cc;
#pragma unroll
    for (int p = 0; p < 4; ++p) {
        const float4 v = *(const float4*)(Wp + (size_t)(16 * p) * IN_DIM);
        const int dl = g + 16 * p;
        tile[dl][cc]     = v.x;
        tile[dl][cc + 1] = v.y;
        tile[dl][cc + 2] = v.z;
        tile[dl][cc + 3] = v.w;
    }
    __syncthreads();

    const int c8 = t & 7;                 // 8-elem d-chunk within the 64-d tile
    const int go = goff8((d0 >> 3) + c8); // byte offset within the protos row
#pragma unroll
    for (int p = 0; p < 2; ++p) {
        const int cr = (t >> 3) + 32 * p; // c-row 0..63
        float v[8];
        float ss = 0.f;
#pragma unroll
        for (int j = 0; j < 8; ++j) {     // banks (8c8+j+cr)%32 -> 2-way, free
            v[j] = tile[8 * c8 + j][cr];
            ss += v[j] * v[j];
        }
        const int o = 2 * (c0 + cr) + r;
        uint2 pk;
        pk.x = pk4(16.f * v[0], 16.f * v[1], 16.f * v[2], 16.f * v[3]);
        pk.y = pk4(16.f * v[4], 16.f * v[5], 16.f * v[6], 16.f * v[7]);
        *(uint2*)(protos + (size_t)o * IN_DIM + go) = pk;
        ss += __shfl_xor(ss, 1);
        ss += __shfl_xor(ss, 2);
        ss += __shfl_xor(ss, 4);
        if (c8 == 0) psq_part[(size_t)blockIdx.y * OUT_DIM + o] = ss;
    }
}

// --------------------------------------------------------------------------
// Kernel 2: fp8 GEMM + epilogue, K-SPLIT-4.
// out[b][o] = 0.125*acc - x_sq[b] - psb[o]
// Block 64M x 64N, 1024 blocks (4/CU, 4 waves/SIMD). Each wave computes the
// FULL 64x64 tile (4x4 MFMA 16x16x32 fp8) over its K-quarter: frag reads
// 0.25 b128/MFMA (R7: 0.375, -33% of the dominant LDS-read term); 8 iters
// of BK=256 halve the barrier count. Cross-wave reduce: wave i owns out-row
// band i*16..+15; partials transit 32 KB LDS in 2 j-phases, 16B/lane
// conflict-free. psb (bias + sum psq_part) computed once per block into LDS.
// --------------------------------------------------------------------------
extern "C" __global__ __launch_bounds__(256, 4) void gemm_epi(
        const unsigned char* __restrict__ A,
        const unsigned char* __restrict__ Bt,
        const float* __restrict__ x_sq,
        const float* __restrict__ psq_part,
        const float* __restrict__ bias,
        float* __restrict__ out) {
    __shared__ __align__(16) unsigned char smem[32768];
    __shared__ float psb_s[64];
    unsigned char* lA = smem;            // 16 KB: 64 rows x 256 B
    unsigned char* lB = smem + 16384;    // 16 KB

    const int lid = blockIdx.x;          // XCD swizzle: XCD k owns n-tiles [8k,8k+8)
    const int xcd = lid & 7;
    const int wi  = lid >> 3;
    const int nt  = xcd * 8 + (wi & 7);
    const int mt  = wi >> 3;
    const int m0 = mt * 64;
    const int n0 = nt * 64;

    const int t = threadIdx.x;
    const int wave = t >> 6;
    const int lane = t & 63;
    const int ln = lane & 15;
    const int qd = lane >> 4;

    // per-block psb: col = n0 + (t>>2), quarter q = t&3 covers dt = 8q..8q+7
    {
        const int col = n0 + (t >> 2);
        const int q = t & 3;
        float s = (q == 0) ? bias[col] : 0.f;
#pragma unroll
        for (int dt = 0; dt < 8; ++dt)
            s += psq_part[(size_t)(8 * q + dt) * OUT_DIM + col];
        s += __shfl_xor(s, 1);
        s += __shfl_xor(s, 2);
        if (q == 0) psb_s[t >> 2] = s;
    }   // published by the first __syncthreads below

    // staging: thread t -> rows rS+16j (j=0..3), phys granule t&15;
    // logical granule lS = (t&15) ^ (row&15) = (t&15) ^ rS (const in j).
    const int rS = t >> 4;
    const int lS = (t & 15) ^ rS;
    const unsigned char* gA = A  + (size_t)(m0 + rS) * IN_DIM + lS * 16;
    const unsigned char* gB = Bt + (size_t)(n0 + rS) * IN_DIM + lS * 16;

    const int pbase = wave * 4 + qd;     // logical frag granule position

    f32x4 acc[4][4] = {};

    for (int it = 0; it < 8; ++it) {     // BK=256 staged; wave owns blocks 2w,2w+1
#pragma unroll
        for (int j = 0; j < 4; ++j) {
            async16(gA + (size_t)(16 * j) * IN_DIM + it * 256, lA + j * 4096 + t * 16);
            async16(gB + (size_t)(16 * j) * IN_DIM + it * 256, lB + j * 4096 + t * 16);
        }
        __syncthreads();                 // vmcnt drain: tile visible

        llx2 af[4], bf[4];
#pragma unroll
        for (int i = 0; i < 4; ++i)
            af[i] = *(const llx2*)(lA + (i * 16 + ln) * 256 + ((pbase ^ ln) * 16));
#pragma unroll
        for (int j = 0; j < 4; ++j)
            bf[j] = *(const llx2*)(lB + (j * 16 + ln) * 256 + ((pbase ^ ln) * 16));
#pragma unroll
        for (int kk = 0; kk < 2; ++kk)
#pragma unroll
            for (int i = 0; i < 4; ++i)
#pragma unroll
                for (int j = 0; j < 4; ++j)
                    acc[i][j] = __builtin_amdgcn_mfma_f32_16x16x32_fp8_fp8(
                                    af[i][kk], bf[j][kk], acc[i][j], 0, 0, 0);
        __syncthreads();                 // reads done before next stage
    }

    // cross-wave reduction: wave w owns out rows [w*16, w*16+16).
    // 2 phases over j-pairs; region (i, src-wave, jj) = 1 KB, 16B/lane.
#pragma unroll
    for (int jp = 0; jp < 2; ++jp) {
        if (jp) __syncthreads();         // phase-0 reads done before overwrite
#pragma unroll
        for (int i = 0; i < 4; ++i)
            if (i != wave) {
#pragma unroll
                for (int jj = 0; jj < 2; ++jj)
                    *(f32x4*)(smem + (i * 4 + wave) * 2048 + jj * 1024 + lane * 16) =
                        acc[i][2 * jp + jj];
            }
        __syncthreads();
#pragma unroll
        for (int jj = 0; jj < 2; ++jj) {
            const int j = 2 * jp + jj;
            f32x4 s = acc[wave][j];
#pragma unroll
            for (int ww = 0; ww < 4; ++ww)
                if (ww != wave) {
                    const f32x4 o4 = *(const f32x4*)(smem + (wave * 4 + ww) * 2048 +
                                                     jj * 1024 + lane * 16);
                    s[0] += o4[0]; s[1] += o4[1]; s[2] += o4[2]; s[3] += o4[3];
                }
            const int col = n0 + j * 16 + ln;
            const float pb = psb_s[j * 16 + ln];
            const int row0 = m0 + wave * 16 + qd * 4;
#pragma unroll
            for (int rr = 0; rr < 4; ++rr)
                out[(size_t)(row0 + rr) * OUT_DIM + col] =
                    0.125f * s[rr] - x_sq[row0 + rr] - pb;
        }
    }
}

// --------------------------------------------------------------------------
extern "C" void kernel_launch(void* const* d_in, const int* in_sizes, int n_in,
                              void* d_out, int out_size, void* d_ws, size_t ws_size,
                              hipStream_t stream) {
    const float* x    = (const float*)d_in[0];   // [1024, 2048]
    const float* W    = (const float*)d_in[1];   // [4096, 2048]
    const float* bias = (const float*)d_in[2];   // [4096]
    float* out = (float*)d_out;

    char* ws = (char*)d_ws;
    unsigned char* protos = (unsigned char*)ws;                               // 8 MB
    unsigned char* xb     = (unsigned char*)(ws + (size_t)8 * 1024 * 1024);   // 2 MB
    float* x_sq           = (float*)(ws + (size_t)10 * 1024 * 1024);          // 4 KB
    float* psq_part       = (float*)(ws + (size_t)10 * 1024 * 1024 + 65536);  // 512 KB

    prep<<<dim3(32, 32, 3), 256, 0, stream>>>(W, x, protos, xb, psq_part, x_sq);
    gemm_epi<<<dim3(1024), 256, 0, stream>>>(xb, protos, x_sq, psq_part, bias, out);
}

// Round 9
// 106.368 us; speedup vs baseline: 2.2193x; 2.2193x over previous
//
#include <hip/hip_runtime.h>

#define IN_DIM  2048
#define OUT_DIM 4096

typedef float     f32x4 __attribute__((ext_vector_type(4)));
typedef long long llx2  __attribute__((ext_vector_type(2)));

// pack 4 fp32 -> 4 fp8 e4m3 (RNE, HW)
__device__ __forceinline__ unsigned int pk4(float a, float b, float c, float d) {
    int v = __builtin_amdgcn_cvt_pk_fp8_f32(a, b, 0, false);   // bytes 0-1
    v     = __builtin_amdgcn_cvt_pk_fp8_f32(c, d, v, true);    // bytes 2-3
    return (unsigned int)v;
}

// async global->LDS, 16B/lane; LDS dest must be wave-uniform base + lane*16
__device__ __forceinline__ void async16(const void* g, void* l) {
    __builtin_amdgcn_global_load_lds(
        (const __attribute__((address_space(1))) unsigned int*)g,
        (__attribute__((address_space(3))) unsigned int*)l,
        16, 0, 0);
}

// k-interleaved fp8 row layout: within each 64B-aligned k-block, memory
// 8B-granule g holds logical k-chunk c(g) = (g>>1) + 4*(g&1); inverse
// g(c) = 2*(c&3)+(c>>2).  => 16B position p holds chunks {p, p+4}, i.e. the
// (kk=0,qd=p) and (kk=1,qd=p) fragments: one ds_read_b128 = 2 fp8 fragments.
__device__ __forceinline__ int gmem_of(int c) { return 2 * (c & 3) + (c >> 2); }

// --------------------------------------------------------------------------
// Kernel 1: fused prep (2 dispatches total for the whole problem).
//  z<2  : transpose slice — W [4096][2048] fp32 -> protos fp8 (x16 scale,
//         k-interleaved), protos[2c+r][d] = fp8(16*W[r*2048+d][c]); exact
//         fp32 partial sumsq -> psq_part[dtile][o] (no atomics, no zeroing).
//  z==2 : xcast — x row b -> xb fp8 (k-interleaved), x_sq[b] exact fp32.
// grid (32, 32, 3) x 256 threads
// --------------------------------------------------------------------------
extern "C" __global__ __launch_bounds__(256) void prep(
        const float* __restrict__ W, const float* __restrict__ x,
        unsigned char* __restrict__ protos, unsigned char* __restrict__ xb,
        float* __restrict__ psq_part, float* __restrict__ x_sq) {
    __shared__ float tile[64][65];   // [d][c], +1 pad (z==2 uses [0][0..3])
    const int t = threadIdx.x;

    if (blockIdx.z == 2) {
        const int b = blockIdx.x + 32 * blockIdx.y;
        const float* xp = x + (size_t)b * IN_DIM + t * 8;
        const float4 v0 = ((const float4*)xp)[0];
        const float4 v1 = ((const float4*)xp)[1];
        uint2 pk;
        pk.x = pk4(v0.x, v0.y, v0.z, v0.w);
        pk.y = pk4(v1.x, v1.y, v1.z, v1.w);
        // t*8 elems = k-block t>>3, chunk t&7 -> interleaved granule position
        *(uint2*)(xb + (size_t)b * IN_DIM + (t >> 3) * 64 + gmem_of(t & 7) * 8) = pk;

        float s = v0.x * v0.x + v0.y * v0.y + v0.z * v0.z + v0.w * v0.w
                + v1.x * v1.x + v1.y * v1.y + v1.z * v1.z + v1.w * v1.w;
#pragma unroll
        for (int off = 32; off > 0; off >>= 1) s += __shfl_down(s, off);
        const int lane = t & 63, w = t >> 6;
        if (lane == 0) tile[0][w] = s;
        __syncthreads();
        if (t == 0) x_sq[b] = tile[0][0] + tile[0][1] + tile[0][2] + tile[0][3];
        return;
    }

    const int r  = blockIdx.z;
    const int c0 = blockIdx.x * 64;
    const int d0 = blockIdx.y * 64;
    const int g  = t >> 4;
    const int cc = (t & 15) * 4;

    const float* Wp = W + (size_t)(r * IN_DIM + d0 + g) * IN_DIM + c0 + cc;
#pragma unroll
    for (int p = 0; p < 4; ++p) {
        const float4 v = *(const float4*)(Wp + (size_t)(16 * p) * IN_DIM);
        const int dl = g + 16 * p;
        tile[dl][cc]     = v.x;
        tile[dl][cc + 1] = v.y;
        tile[dl][cc + 2] = v.z;
        tile[dl][cc + 3] = v.w;
    }
    __syncthreads();

    const int c8 = t & 7;                 // k-chunk within the 64-d tile
    const int gm = gmem_of(c8);
#pragma unroll
    for (int p = 0; p < 2; ++p) {
        const int cr = (t >> 3) + 32 * p; // c-row 0..63
        float v[8];
        float ss = 0.f;
#pragma unroll
        for (int j = 0; j < 8; ++j) {     // banks (8c8+j+cr)%32 -> 2-way, free
            v[j] = tile[8 * c8 + j][cr];
            ss += v[j] * v[j];
        }
        const int o = 2 * (c0 + cr) + r;
        uint2 pk;
        pk.x = pk4(16.f * v[0], 16.f * v[1], 16.f * v[2], 16.f * v[3]);
        pk.y = pk4(16.f * v[4], 16.f * v[5], 16.f * v[6], 16.f * v[7]);
        *(uint2*)(protos + (size_t)o * IN_DIM + d0 + gm * 8) = pk;
        ss += __shfl_xor(ss, 1);
        ss += __shfl_xor(ss, 2);
        ss += __shfl_xor(ss, 4);
        if (c8 == 0) psq_part[(size_t)blockIdx.y * OUT_DIM + o] = ss;
    }
}

// --------------------------------------------------------------------------
// Kernel 2: fp8 GEMM + epilogue — measured-best structure (R7).
// out[b][o] = 0.125*acc - x_sq[b] - (sum_dt psq_part[dt][o] + bias[o])
// Block 64M x 64N, 1024 blocks (4/CU, 4 waves/SIMD). Wave w: kh=w&1 owns
// K-half, nh=w>>1 owns 32 N-cols; wave tile 64x32 = 4x2 MFMA 16x16x32 fp8.
// LDS row = 128B (2 k-halves x 64B k-interleaved blocks); position swizzle
// p = l ^ (row&7) on the GLOBAL side of global_load_lds -> staging stays
// lane-contiguous, frag b128 reads are 2-way (free, m136).
// R8 lesson: 64x64 wave tiles (acc[4][4]=64 regs) spill under the (256,4)
// 128-VGPR cap -> 556 MB scratch traffic. 4x2 acc is the pressure sweet spot.
// --------------------------------------------------------------------------
extern "C" __global__ __launch_bounds__(256, 4) void gemm_epi(
        const unsigned char* __restrict__ A,
        const unsigned char* __restrict__ Bt,
        const float* __restrict__ x_sq,
        const float* __restrict__ psq_part,
        const float* __restrict__ bias,
        float* __restrict__ out) {
    __shared__ __align__(16) unsigned char smem[16384];
    unsigned char* lA = smem;           // 8 KB: 64 rows x 128 B
    unsigned char* lB = smem + 8192;    // 8 KB

    const int lid = blockIdx.x;          // XCD swizzle: XCD k owns n-tiles [8k,8k+8)
    const int xcd = lid & 7;
    const int wi  = lid >> 3;
    const int nt  = xcd * 8 + (wi & 7);
    const int mt  = wi >> 3;
    const int m0 = mt * 64;
    const int n0 = nt * 64;

    const int t = threadIdx.x;
    // staging: thread t owns LDS bytes [16t,16t+16) and [4096+16t,+16) of
    // lA/lB. off -> row=off>>7, phys pos p=(off>>4)&7; logical l = p^(row&7);
    // l -> k-half l>>2, 16B-chunk l&3 of the row's 64B k-block.
    const int rS = t >> 3;               // row 0..31 (2nd chunk: +32, same &7)
    const int pS = t & 7;
    const int lS = pS ^ (rS & 7);
    const size_t goff = (size_t)(lS >> 2) * 1024 + (lS & 3) * 16;
    const unsigned char* gA0 = A  + (size_t)(m0 + rS) * IN_DIM + goff;
    const unsigned char* gA1 = gA0 + (size_t)32 * IN_DIM;
    const unsigned char* gB0 = Bt + (size_t)(n0 + rS) * IN_DIM + goff;
    const unsigned char* gB1 = gB0 + (size_t)32 * IN_DIM;
    unsigned char* lAd = lA + t * 16;
    unsigned char* lBd = lB + t * 16;

    const int wave = t >> 6;
    const int lane = t & 63;
    const int kh = wave & 1;             // K-half this wave owns
    const int nh = wave >> 1;            // N-half this wave owns
    const int ln = lane & 15;
    const int qd = lane >> 4;
    const int pr = (kh * 4 + qd) ^ (ln & 7);   // phys 16B pos for frag reads

    f32x4 acc[4][2] = {};

    for (int it = 0; it < 16; ++it) {    // BK=64 per half per iter
        async16(gA0, lAd); async16(gA1, lAd + 4096);
        async16(gB0, lBd); async16(gB1, lBd + 4096);
        gA0 += 64; gA1 += 64; gB0 += 64; gB1 += 64;
        __syncthreads();                 // vmcnt drain: tile visible

        llx2 af[4], bf[2];
#pragma unroll
        for (int i = 0; i < 4; ++i)
            af[i] = *(const llx2*)(lA + (i * 16 + ln) * 128 + pr * 16);
#pragma unroll
        for (int j = 0; j < 2; ++j)
            bf[j] = *(const llx2*)(lB + (nh * 32 + j * 16 + ln) * 128 + pr * 16);
#pragma unroll
        for (int kk = 0; kk < 2; ++kk)
#pragma unroll
            for (int i = 0; i < 4; ++i)
#pragma unroll
                for (int j = 0; j < 2; ++j)
                    acc[i][j] = __builtin_amdgcn_mfma_f32_16x16x32_fp8_fp8(
                                    af[i][kk], bf[j][kk], acc[i][j], 0, 0, 0);
        __syncthreads();                 // reads done before next stage
    }

    // cross-K-half reduction: kh=1 waves dump acc to LDS, kh=0 waves finish.
    if (kh == 1) {
#pragma unroll
        for (int i = 0; i < 4; ++i)
#pragma unroll
            for (int j = 0; j < 2; ++j)
                *(f32x4*)(smem + nh * 8192 + (i * 2 + j) * 1024 + lane * 16) =
                    acc[i][j];
    }
    __syncthreads();
    if (kh == 0) {
#pragma unroll
        for (int j = 0; j < 2; ++j) {
            const int col = n0 + nh * 32 + j * 16 + ln;
            float pb = bias[col];
#pragma unroll
            for (int dt = 0; dt < 32; ++dt)
                pb += psq_part[(size_t)dt * OUT_DIM + col];
#pragma unroll
            for (int i = 0; i < 4; ++i) {
                const f32x4 o4 = *(const f32x4*)(smem + nh * 8192 +
                                                 (i * 2 + j) * 1024 + lane * 16);
                const int row0 = m0 + i * 16 + qd * 4;
#pragma unroll
                for (int rr = 0; rr < 4; ++rr) {
                    const int row = row0 + rr;
                    out[(size_t)row * OUT_DIM + col] =
                        0.125f * (acc[i][j][rr] + o4[rr]) - x_sq[row] - pb;
                }
            }
        }
    }
}

// --------------------------------------------------------------------------
extern "C" void kernel_launch(void* const* d_in, const int* in_sizes, int n_in,
                              void* d_out, int out_size, void* d_ws, size_t ws_size,
                              hipStream_t stream) {
    const float* x    = (const float*)d_in[0];   // [1024, 2048]
    const float* W    = (const float*)d_in[1];   // [4096, 2048]
    const float* bias = (const float*)d_in[2];   // [4096]
    float* out = (float*)d_out;

    char* ws = (char*)d_ws;
    unsigned char* protos = (unsigned char*)ws;                               // 8 MB
    unsigned char* xb     = (unsigned char*)(ws + (size_t)8 * 1024 * 1024);   // 2 MB
    float* x_sq           = (float*)(ws + (size_t)10 * 1024 * 1024);          // 4 KB
    float* psq_part       = (float*)(ws + (size_t)10 * 1024 * 1024 + 65536);  // 512 KB

    prep<<<dim3(32, 32, 3), 256, 0, stream>>>(W, x, protos, xb, psq_part, x_sq);
    gemm_epi<<<dim3(1024), 256, 0, stream>>>(xb, protos, x_sq, psq_part, bias, out);
}